// Round 5
// baseline (824.817 us; speedup 1.0000x reference)
//
#include <hip/hip_runtime.h>
#include <cstdint>
#include <cstddef>

// Problem constants
constexpr int Bc  = 4;
constexpr int Sc  = 2048;
constexpr int DMc = 1024;   // d_model
constexpr int Hc  = 16;     // heads
constexpr int DHc = 64;     // head dim
constexpr int BHc = Bc * Hc;

typedef float f32x4  __attribute__((ext_vector_type(4)));
typedef short bf16x8 __attribute__((ext_vector_type(8)));

// f32 -> bf16 (RNE)
static __device__ __forceinline__ short f2bf(float x) {
  uint32_t u = __builtin_bit_cast(uint32_t, x);
  u += 0x7fffu + ((u >> 16) & 1u);
  return (short)(u >> 16);
}

static __device__ __forceinline__ f32x4 mfma16(bf16x8 a, bf16x8 b, f32x4 c) {
  return __builtin_amdgcn_mfma_f32_16x16x32_bf16(a, b, c, 0, 0, 0);
}

// async global->LDS, 16B per lane. LDS dest is wave-uniform base + lane*16.
static __device__ __forceinline__ void gload16(const short* g, short* l) {
  __builtin_amdgcn_global_load_lds(
      (const __attribute__((address_space(1))) void*)g,
      (__attribute__((address_space(3))) void*)l, 16, 0, 0);
}

// ---------------- dtype conversion: f32 -> bf16, 4 elems/thread ----------------
__global__ __launch_bounds__(256) void k_cvt(const float* __restrict__ in,
                                             short* __restrict__ out) {
  int i = blockIdx.x * 256 + threadIdx.x;
  float4 v = reinterpret_cast<const float4*>(in)[i];
  short4 o;
  o.x = f2bf(v.x); o.y = f2bf(v.y); o.z = f2bf(v.z); o.w = f2bf(v.w);
  reinterpret_cast<short4*>(out)[i] = o;
}

// ---------------- mask bit-pack: int32 -> 1 bit ----------------
__global__ __launch_bounds__(256) void k_pack(const int* __restrict__ m,
                                              uint32_t* __restrict__ bits) {
  size_t i = (size_t)blockIdx.x * 256 + threadIdx.x;
  uint64_t b = __ballot(m[i] != 0);
  int lane = threadIdx.x & 63;
  if (lane == 0)  bits[i >> 5] = (uint32_t)b;
  if (lane == 32) bits[i >> 5] = (uint32_t)(b >> 32);
}

// ---------------- GEMM: Y[m,e] = sum_d A[m,d] * Bt[e,d] ----------------
// 128x128 tile, BK=32, 256 threads (4 waves, 2x2), each wave 64x64.
__global__ __launch_bounds__(256) void k_gemm(const short* __restrict__ A,
                                              const short* __restrict__ Bt,
                                              void* __restrict__ out, int mode) {
  __shared__ __align__(16) short lA[128 * 32];
  __shared__ __align__(16) short lB[128 * 32];
  const int bm = blockIdx.x * 128, bn = blockIdx.y * 128;
  const int lane = threadIdx.x & 63, w = threadIdx.x >> 6;
  const int wr = w >> 1, wc = w & 1;
  const int r = lane & 15, g = lane >> 4;
  const int lrow = lane >> 2;                       // staging row within 16-row chunk
  const int lsl  = (lane & 3) ^ ((lane >> 3) & 3);  // pre-swizzled global k-slot
  const int rsw  = (r >> 1) & 3;                    // read-side swizzle

  f32x4 acc[4][4] = {};
  const short* Ab = A + (size_t)bm * DMc;
  const short* Bb = Bt + (size_t)bn * DMc;

  for (int k0 = 0; k0 < DMc; k0 += 32) {
    __syncthreads();
    #pragma unroll
    for (int c = 0; c < 2; c++) {
      const int rbase = c * 64 + w * 16;
      gload16(Ab + (size_t)(rbase + lrow) * DMc + k0 + lsl * 8, lA + rbase * 32);
      gload16(Bb + (size_t)(rbase + lrow) * DMc + k0 + lsl * 8, lB + rbase * 32);
    }
    __syncthreads();

    bf16x8 af[4], bfr[4];
    #pragma unroll
    for (int i = 0; i < 4; i++) {
      const int arow = wr * 64 + i * 16 + r;
      af[i]  = *reinterpret_cast<const bf16x8*>(lA + arow * 32 + (g ^ rsw) * 8);
      const int brow = wc * 64 + i * 16 + r;
      bfr[i] = *reinterpret_cast<const bf16x8*>(lB + brow * 32 + (g ^ rsw) * 8);
    }
    #pragma unroll
    for (int i = 0; i < 4; i++)
      #pragma unroll
      for (int n = 0; n < 4; n++) acc[i][n] = mfma16(af[i], bfr[n], acc[i][n]);
  }

  #pragma unroll
  for (int i = 0; i < 4; i++) {
    #pragma unroll
    for (int n = 0; n < 4; n++) {
      const int col = bn + wc * 64 + n * 16 + r;
      #pragma unroll
      for (int j = 0; j < 4; j++) {
        const int m = bm + wr * 64 + i * 16 + g * 4 + j;
        if (mode == 2) {
          reinterpret_cast<float*>(out)[(size_t)m * DMc + col] = acc[i][n][j];
        } else {
          const int b = m >> 11, s = m & (Sc - 1);
          const int h = col >> 6, d = col & (DHc - 1);
          size_t idx = (mode == 1)
              ? ((size_t)(b * Hc + h) * DHc + d) * Sc + s     // Vt [BH][64][S]
              : ((size_t)(b * Hc + h) * Sc + s) * DHc + d;    // Q/K [BH][S][64]
          reinterpret_cast<short*>(out)[idx] = f2bf(acc[i][n][j]);
        }
      }
    }
  }
}

// ---------------- fused scores + mask + softmax + attn-write + PV ----------------
// grid (S/16, BH), block 512 (8 waves). Block: 16 q-rows, full 2048 k-cols.
// No-max softmax (exp2 direct; safe for |scores/8| << 88): per-wave phases run
// with NO cross-wave sync until the single sum-publish barrier. PV uses
// unnormalized P (bf16, per-wave LDS window); ctx partials normalized at the
// cross-wave reduce. attn store re-reads own P from LDS (frees sc registers).
__global__ __launch_bounds__(512, 4) void k_attn(const short* __restrict__ Qb,
                                                 const short* __restrict__ Kb,
                                                 const uint32_t* __restrict__ pbits,
                                                 const short* __restrict__ Vt,
                                                 float* __restrict__ attn,
                                                 short* __restrict__ ctx) {
  __shared__ __align__(16) short pbuf[8][4096];  // 64 KiB: per-wave 16x256 bf16 P
  __shared__ float reds[8][16];
  // rbuf (33.3 KiB) aliases pbuf; only touched after barrier #2
  float (*rbuf)[16][65] = reinterpret_cast<float (*)[16][65]>(&pbuf[0][0]);

  const int qb = blockIdx.x * 16;
  const int bh = blockIdx.y;
  const int b = bh >> 4, h = bh & 15;
  const int lane = threadIdx.x & 63, w = threadIdx.x >> 6;
  const int r = lane & 15, g = lane >> 4;

  // mask words early (row q=qb+r, 32B contiguous per lane)
  const uint32_t* mrow = pbits + ((size_t)b * Sc + qb + r) * (Sc / 32) + w * 8;
  const uint4 m0 = *reinterpret_cast<const uint4*>(mrow);
  const uint4 m1 = *reinterpret_cast<const uint4*>(mrow + 4);

  // Q B-fragment: lane(r,g) = Q[qb+r][g*8..g*8+7] (+32 for second half)
  const short* qrow = Qb + ((size_t)bh * Sc + qb + r) * DHc;
  const bf16x8 qf0 = *reinterpret_cast<const bf16x8*>(qrow + g * 8);
  const bf16x8 qf1 = *reinterpret_cast<const bf16x8*>(qrow + g * 8 + 32);
  const short* kbase = Kb + (size_t)bh * Sc * DHc;

  // swapped QK^T (mfma(K,Q)): lane holds 4 consecutive k of q=qb+r.
  // 4 batches of 4 t-tiles: 8 K-loads in flight per batch.
  f32x4 sc[16];
  #pragma unroll
  for (int bt = 0; bt < 4; bt++) {
    bf16x8 kf[4][2];
    #pragma unroll
    for (int tt = 0; tt < 4; tt++) {
      const short* krow = kbase + (size_t)((w * 16 + bt * 4 + tt) * 16 + r) * DHc;
      kf[tt][0] = *reinterpret_cast<const bf16x8*>(krow + g * 8);
      kf[tt][1] = *reinterpret_cast<const bf16x8*>(krow + g * 8 + 32);
    }
    #pragma unroll
    for (int tt = 0; tt < 4; tt++) {
      f32x4 a = {};
      a = mfma16(kf[tt][0], qf0, a);
      a = mfma16(kf[tt][1], qf1, a);
      sc[bt * 4 + tt] = a;
    }
  }

  // mask apply
  const uint32_t mw[8] = {m0.x, m0.y, m0.z, m0.w, m1.x, m1.y, m1.z, m1.w};
  #pragma unroll
  for (int t = 0; t < 16; t++) {
    #pragma unroll
    for (int j = 0; j < 4; j++) {
      // k = w*256 + t*16 + g*4 + j ; word = t>>1 ; bit = (t&1)*16 + g*4 + j
      if ((mw[t >> 1] >> ((t & 1) * 16 + g * 4 + j)) & 1u) sc[t][j] = -8e9f;
    }
  }

  // exp (no max-sub; exp(x/8) = 2^(x*log2e/8)) + row sum + pack P -> LDS
  constexpr float SCL = 0.18033688f;  // log2(e)/8
  float psum = 0.f;
  #pragma unroll
  for (int t = 0; t < 16; t++) {
    float e0 = __builtin_exp2f(sc[t][0] * SCL);
    float e1 = __builtin_exp2f(sc[t][1] * SCL);
    float e2 = __builtin_exp2f(sc[t][2] * SCL);
    float e3 = __builtin_exp2f(sc[t][3] * SCL);
    psum += (e0 + e1) + (e2 + e3);
    uint32_t lo = (uint32_t)(uint16_t)f2bf(e0) | ((uint32_t)(uint16_t)f2bf(e1) << 16);
    uint32_t hi = (uint32_t)(uint16_t)f2bf(e2) | ((uint32_t)(uint16_t)f2bf(e3) << 16);
    uint64_t pk = (uint64_t)lo | ((uint64_t)hi << 32);
    const int slot = (t * 4 + g) ^ r;  // conflict-reduced write swizzle
    *reinterpret_cast<uint64_t*>(&pbuf[w][r * 256 + slot * 4]) = pk;
  }
  psum += __shfl_xor(psum, 16);
  psum += __shfl_xor(psum, 32);
  if (lane < 16) reds[w][r] = psum;

  // PV (unnormalized) over this wave's k-window; 2 batches of 4 kt (16 V loads in flight)
  const short* vb = Vt + (size_t)bh * DHc * Sc + w * 256;
  f32x4 pacc[4] = {};
  #pragma unroll
  for (int kb2 = 0; kb2 < 2; kb2++) {
    bf16x8 vf[4][4];
    #pragma unroll
    for (int ktt = 0; ktt < 4; ktt++) {
      const int kt = kb2 * 4 + ktt;
      #pragma unroll
      for (int n = 0; n < 4; n++)
        vf[ktt][n] = *reinterpret_cast<const bf16x8*>(
            vb + (size_t)(n * 16 + r) * Sc + kt * 32 + g * 8);
    }
    #pragma unroll
    for (int ktt = 0; ktt < 4; ktt++) {
      const int kt = kb2 * 4 + ktt;
      const int s0 = (kt * 8 + g * 2) ^ r;
      const int s1 = (kt * 8 + g * 2 + 1) ^ r;
      union { uint64_t q[2]; bf16x8 v; } u;
      u.q[0] = *reinterpret_cast<const uint64_t*>(&pbuf[w][r * 256 + s0 * 4]);
      u.q[1] = *reinterpret_cast<const uint64_t*>(&pbuf[w][r * 256 + s1 * 4]);
      #pragma unroll
      for (int n = 0; n < 4; n++) pacc[n] = mfma16(u.v, vf[ktt][n], pacc[n]);
    }
  }

  __syncthreads();  // #1: publish reds (all waves' psum)

  float rsum = 0.f;
  #pragma unroll
  for (int ww = 0; ww < 8; ww++) rsum += reds[ww][r];
  const float rinv = 1.0f / rsum;

  // attn store: re-read own P from LDS, normalize, nontemporal f32x4
  float* arow_out = attn + ((size_t)bh * Sc + qb + r) * Sc + w * 256;
  #pragma unroll
  for (int t = 0; t < 16; t++) {
    const int slot = (t * 4 + g) ^ r;
    uint64_t pk = *reinterpret_cast<const uint64_t*>(&pbuf[w][r * 256 + slot * 4]);
    uint32_t lo = (uint32_t)pk, hi = (uint32_t)(pk >> 32);
    f32x4 o;
    o[0] = __builtin_bit_cast(float, lo << 16) * rinv;
    o[1] = __builtin_bit_cast(float, lo & 0xffff0000u) * rinv;
    o[2] = __builtin_bit_cast(float, hi << 16) * rinv;
    o[3] = __builtin_bit_cast(float, hi & 0xffff0000u) * rinv;
    __builtin_nontemporal_store(o, reinterpret_cast<f32x4*>(arow_out + t * 16 + g * 4));
  }

  // rinv for ctx rows q=g*4+j (lanes 0..15 hold rinv for row r=lane)
  float riv[4];
  #pragma unroll
  for (int j = 0; j < 4; j++) riv[j] = __shfl(rinv, g * 4 + j);

  __syncthreads();  // #2: all attn re-reads of pbuf done -> rbuf may overwrite

  #pragma unroll
  for (int n = 0; n < 4; n++)
    #pragma unroll
    for (int j = 0; j < 4; j++) rbuf[w][g * 4 + j][n * 16 + r] = pacc[n][j] * riv[j];

  __syncthreads();  // #3: rbuf complete

  const int tq = threadIdx.x >> 5, td = (threadIdx.x & 31) * 2;
  float s0 = 0.f, s1 = 0.f;
  #pragma unroll
  for (int ww = 0; ww < 8; ww++) {
    s0 += rbuf[ww][tq][td];
    s1 += rbuf[ww][tq][td + 1];
  }
  uint32_t pk = (uint32_t)(uint16_t)f2bf(s0) | ((uint32_t)(uint16_t)f2bf(s1) << 16);
  *reinterpret_cast<uint32_t*>(ctx + ((size_t)b * Sc + qb + tq) * DMc + h * DHc + td) = pk;
}

// ---------------- residual + LayerNorm ----------------
__global__ __launch_bounds__(256) void k_ln(const float* __restrict__ y,
                                            const float* __restrict__ resid,
                                            float* __restrict__ out) {
  const int m = blockIdx.x, t = threadIdx.x;
  const float4 a = reinterpret_cast<const float4*>(y + (size_t)m * DMc)[t];
  const float4 b = reinterpret_cast<const float4*>(resid + (size_t)m * DMc)[t];
  float x0 = a.x + b.x, x1 = a.y + b.y, x2 = a.z + b.z, x3 = a.w + b.w;

  float s = x0 + x1 + x2 + x3;
  #pragma unroll
  for (int m2 = 1; m2 < 64; m2 <<= 1) s += __shfl_xor(s, m2);
  __shared__ float red[4];
  __shared__ float red2[4];
  const int w = t >> 6, lane = t & 63;
  if (lane == 0) red[w] = s;
  __syncthreads();
  const float mean = (red[0] + red[1] + red[2] + red[3]) * (1.0f / DMc);

  x0 -= mean; x1 -= mean; x2 -= mean; x3 -= mean;
  float s2 = x0 * x0 + x1 * x1 + x2 * x2 + x3 * x3;
  #pragma unroll
  for (int m2 = 1; m2 < 64; m2 <<= 1) s2 += __shfl_xor(s2, m2);
  if (lane == 0) red2[w] = s2;
  __syncthreads();
  const float var = (red2[0] + red2[1] + red2[2] + red2[3]) * (1.0f / DMc);
  const float rstd = rsqrtf(var + 1e-5f);

  float4 o;
  o.x = x0 * rstd; o.y = x1 * rstd; o.z = x2 * rstd; o.w = x3 * rstd;
  reinterpret_cast<float4*>(out + (size_t)m * DMc)[t] = o;
}

extern "C" void kernel_launch(void* const* d_in, const int* in_sizes, int n_in,
                              void* d_out, int out_size, void* d_ws, size_t ws_size,
                              hipStream_t stream) {
  const float* inQ = (const float*)d_in[0];
  const float* inK = (const float*)d_in[1];
  const float* inV = (const float*)d_in[2];
  const int*   msk = (const int*)d_in[3];
  const float* WQ  = (const float*)d_in[4];
  const float* WK  = (const float*)d_in[5];
  const float* WV  = (const float*)d_in[6];
  const float* Wfc = (const float*)d_in[7];

  float* out_ln   = (float*)d_out;                       // [B,S,1024] f32
  float* out_attn = out_ln + (size_t)Bc * Sc * DMc;      // [B,H,S,S] f32

  const size_t NX = (size_t)Bc * Sc * DMc;  // 8,388,608
  const size_t NW = (size_t)DMc * DMc;      // 1,048,576
  short* ws = (short*)d_ws;
  short* XbQ = ws;                 // bf16 inputs
  short* XbK = XbQ + NX;
  short* XbV = XbK + NX;
  short* WQb = XbV + NX;           // bf16 weights
  short* WKb = WQb + NW;
  short* WVb = WKb + NW;
  short* Wfb = WVb + NW;
  short* Qb  = Wfb + NW;           // [BH][S][64]
  short* Kb  = Qb + NX;            // [BH][S][64]
  short* Vt  = Kb + NX;            // [BH][64][S]
  uint32_t* pbits = (uint32_t*)(Vt + NX);  // [B][S][64 words]
  short* ctx = XbV;                // aliases XbV (dead after V-proj)
  float* y   = (float*)XbQ;        // aliases XbQ+XbK (dead after Q/K-proj)

  // 1) f32 -> bf16 conversions + mask pack
  k_cvt<<<dim3((unsigned)(NX / 1024)), 256, 0, stream>>>(inQ, XbQ);
  k_cvt<<<dim3((unsigned)(NX / 1024)), 256, 0, stream>>>(inK, XbK);
  k_cvt<<<dim3((unsigned)(NX / 1024)), 256, 0, stream>>>(inV, XbV);
  k_cvt<<<dim3((unsigned)(NW / 1024)), 256, 0, stream>>>(WQ, WQb);
  k_cvt<<<dim3((unsigned)(NW / 1024)), 256, 0, stream>>>(WK, WKb);
  k_cvt<<<dim3((unsigned)(NW / 1024)), 256, 0, stream>>>(WV, WVb);
  k_cvt<<<dim3((unsigned)(NW / 1024)), 256, 0, stream>>>(Wfc, Wfb);
  k_pack<<<dim3((unsigned)(Bc * Sc * (Sc / 256))), 256, 0, stream>>>(msk, pbits);

  // 2) projections (128x128 tiles)
  dim3 gp(Bc * Sc / 128, DMc / 128);  // (64, 8)
  k_gemm<<<gp, 256, 0, stream>>>(XbQ, WQb, (void*)Qb, 0);
  k_gemm<<<gp, 256, 0, stream>>>(XbK, WKb, (void*)Kb, 0);
  k_gemm<<<gp, 256, 0, stream>>>(XbV, WVb, (void*)Vt, 1);

  // 3) fused scores + softmax + attn write + PV -> ctx
  k_attn<<<dim3(Sc / 16, BHc), 512, 0, stream>>>(Qb, Kb, pbits, Vt, out_attn, ctx);

  // 4) output projection -> y (f32)
  k_gemm<<<gp, 256, 0, stream>>>(ctx, Wfb, (void*)y, 2);

  // 5) residual + LayerNorm -> ln (output 0)
  k_ln<<<dim3(Bc * Sc), 256, 0, stream>>>(y, inQ, out_ln);
}

// Round 6
// 654.050 us; speedup vs baseline: 1.2611x; 1.2611x over previous
//
#include <hip/hip_runtime.h>
#include <cstdint>
#include <cstddef>

// Problem constants
constexpr int Bc  = 4;
constexpr int Sc  = 2048;
constexpr int DMc = 1024;   // d_model
constexpr int Hc  = 16;     // heads
constexpr int DHc = 64;     // head dim
constexpr int BHc = Bc * Hc;

typedef float f32x4  __attribute__((ext_vector_type(4)));
typedef short bf16x8 __attribute__((ext_vector_type(8)));

// f32 -> bf16 (RNE)
static __device__ __forceinline__ short f2bf(float x) {
  uint32_t u = __builtin_bit_cast(uint32_t, x);
  u += 0x7fffu + ((u >> 16) & 1u);
  return (short)(u >> 16);
}

static __device__ __forceinline__ f32x4 mfma16(bf16x8 a, bf16x8 b, f32x4 c) {
  return __builtin_amdgcn_mfma_f32_16x16x32_bf16(a, b, c, 0, 0, 0);
}

// async global->LDS, 16B per lane. LDS dest is wave-uniform base + lane*16.
static __device__ __forceinline__ void gload16(const short* g, short* l) {
  __builtin_amdgcn_global_load_lds(
      (const __attribute__((address_space(1))) void*)g,
      (__attribute__((address_space(3))) void*)l, 16, 0, 0);
}

// ---------------- dtype conversion: f32 -> bf16, 4 elems/thread ----------------
__global__ __launch_bounds__(256) void k_cvt(const float* __restrict__ in,
                                             short* __restrict__ out) {
  int i = blockIdx.x * 256 + threadIdx.x;
  float4 v = reinterpret_cast<const float4*>(in)[i];
  short4 o;
  o.x = f2bf(v.x); o.y = f2bf(v.y); o.z = f2bf(v.z); o.w = f2bf(v.w);
  reinterpret_cast<short4*>(out)[i] = o;
}

// ---------------- mask bit-pack: int32 -> 1 bit ----------------
__global__ __launch_bounds__(256) void k_pack(const int* __restrict__ m,
                                              uint32_t* __restrict__ bits) {
  size_t i = (size_t)blockIdx.x * 256 + threadIdx.x;
  uint64_t b = __ballot(m[i] != 0);
  int lane = threadIdx.x & 63;
  if (lane == 0)  bits[i >> 5] = (uint32_t)b;
  if (lane == 32) bits[i >> 5] = (uint32_t)(b >> 32);
}

// ---------------- GEMM: Y[m,e] = sum_d A[m,d] * Bt[e,d] ----------------
// 128x128 tile, BK=32, 256 threads (4 waves, 2x2), each wave 64x64.
__global__ __launch_bounds__(256) void k_gemm(const short* __restrict__ A,
                                              const short* __restrict__ Bt,
                                              void* __restrict__ out, int mode) {
  __shared__ __align__(16) short lA[128 * 32];
  __shared__ __align__(16) short lB[128 * 32];
  const int bm = blockIdx.x * 128, bn = blockIdx.y * 128;
  const int lane = threadIdx.x & 63, w = threadIdx.x >> 6;
  const int wr = w >> 1, wc = w & 1;
  const int r = lane & 15, g = lane >> 4;
  const int lrow = lane >> 2;                       // staging row within 16-row chunk
  const int lsl  = (lane & 3) ^ ((lane >> 3) & 3);  // pre-swizzled global k-slot
  const int rsw  = (r >> 1) & 3;                    // read-side swizzle

  f32x4 acc[4][4] = {};
  const short* Ab = A + (size_t)bm * DMc;
  const short* Bb = Bt + (size_t)bn * DMc;

  for (int k0 = 0; k0 < DMc; k0 += 32) {
    __syncthreads();
    #pragma unroll
    for (int c = 0; c < 2; c++) {
      const int rbase = c * 64 + w * 16;
      gload16(Ab + (size_t)(rbase + lrow) * DMc + k0 + lsl * 8, lA + rbase * 32);
      gload16(Bb + (size_t)(rbase + lrow) * DMc + k0 + lsl * 8, lB + rbase * 32);
    }
    __syncthreads();

    bf16x8 af[4], bfr[4];
    #pragma unroll
    for (int i = 0; i < 4; i++) {
      const int arow = wr * 64 + i * 16 + r;
      af[i]  = *reinterpret_cast<const bf16x8*>(lA + arow * 32 + (g ^ rsw) * 8);
      const int brow = wc * 64 + i * 16 + r;
      bfr[i] = *reinterpret_cast<const bf16x8*>(lB + brow * 32 + (g ^ rsw) * 8);
    }
    #pragma unroll
    for (int i = 0; i < 4; i++)
      #pragma unroll
      for (int n = 0; n < 4; n++) acc[i][n] = mfma16(af[i], bfr[n], acc[i][n]);
  }

  #pragma unroll
  for (int i = 0; i < 4; i++) {
    #pragma unroll
    for (int n = 0; n < 4; n++) {
      const int col = bn + wc * 64 + n * 16 + r;
      #pragma unroll
      for (int j = 0; j < 4; j++) {
        const int m = bm + wr * 64 + i * 16 + g * 4 + j;
        if (mode == 2) {
          reinterpret_cast<float*>(out)[(size_t)m * DMc + col] = acc[i][n][j];
        } else {
          const int b = m >> 11, s = m & (Sc - 1);
          const int h = col >> 6, d = col & (DHc - 1);
          size_t idx = (mode == 1)
              ? ((size_t)(b * Hc + h) * DHc + d) * Sc + s     // Vt [BH][64][S]
              : ((size_t)(b * Hc + h) * Sc + s) * DHc + d;    // Q/K [BH][S][64]
          reinterpret_cast<short*>(out)[idx] = f2bf(acc[i][n][j]);
        }
      }
    }
  }
}

// ---------------- flash ctx: QK^T + mask + exp + PV, K/V LDS double-buffered ----
// grid (S/128, BH), block 512 (8 waves). Wave w owns q-rows [qbase+w*16, +16),
// sweeps all 2048 k in 32 tiles of 64. K/V tiles staged via global_load_lds
// (linear dest, inverse-swizzled global source: slot ^= row&7; ds_read applies
// the same XOR). P (unnormalized, bf16) lives in per-wave LDS. No cross-wave
// reduction: each wave writes its own ctx rows. Outputs ctx (bf16) and rsum.
__global__ __launch_bounds__(512, 4) void k_flash(const short* __restrict__ Qb,
                                                  const short* __restrict__ Kb,
                                                  const short* __restrict__ Vt,
                                                  const uint32_t* __restrict__ pbits,
                                                  short* __restrict__ ctx,
                                                  float* __restrict__ rsum) {
  __shared__ __align__(16) short kbuf[2][4096];  // [64 k-rows][64 d] x dbuf, 16 KB
  __shared__ __align__(16) short vbuf[2][4096];  // [64 d-rows][64 k] x dbuf, 16 KB
  __shared__ __align__(16) short pbuf[8][1024];  // per-wave [16 q][64 k] bf16, 16 KB

  const int qbase = blockIdx.x * 128;
  const int bh = blockIdx.y;
  const int b = bh >> 4, h = bh & 15;
  const int tid = threadIdx.x;
  const int lane = tid & 63, w = tid >> 6;
  const int r = lane & 15, g = lane >> 4;
  const int rx = r & 7;

  // staging thread->element map: row = tid>>3, slot = (tid&7) ^ (row&7)
  const int srow = tid >> 3;
  const int sslot = (tid & 7) ^ (srow & 7);
  const short* ksrc = Kb + ((size_t)bh * Sc + srow) * DHc + sslot * 8;
  const short* vsrc = Vt + ((size_t)bh * DHc + srow) * Sc + sslot * 8;
  short* const kdst0 = &kbuf[0][w * 512];
  short* const kdst1 = &kbuf[1][w * 512];
  short* const vdst0 = &vbuf[0][w * 512];
  short* const vdst1 = &vbuf[1][w * 512];

  // Q fragment for my 16 rows (q = qbase + w*16 + r)
  const short* qrow = Qb + ((size_t)bh * Sc + qbase + w * 16 + r) * DHc;
  const bf16x8 qf0 = *reinterpret_cast<const bf16x8*>(qrow + g * 8);
  const bf16x8 qf1 = *reinterpret_cast<const bf16x8*>(qrow + g * 8 + 32);

  const uint32_t* mrow = pbits + ((size_t)b * Sc + qbase + w * 16 + r) * (Sc / 32);

  constexpr float SCL = 0.18033688f;  // log2(e)/8
  f32x4 pacc[4] = {};
  float rs = 0.f;

  // prologue: stage kt=0 into buffer 0
  gload16(ksrc, kdst0);
  gload16(vsrc, vdst0);
  __syncthreads();  // compiler drains vmcnt before barrier

  int cur = 0;
  for (int kt = 0; kt < 32; kt++) {
    // issue next tile's stage first (overlaps with this step's compute)
    if (kt + 1 < 32) {
      gload16(ksrc + (size_t)(kt + 1) * 64 * DHc, cur ? kdst0 : kdst1);
      gload16(vsrc + (kt + 1) * 64,               cur ? vdst0 : vdst1);
    }
    const short* kb = kbuf[cur];
    const short* vb = vbuf[cur];

    // QK^T: 4 t-tiles of 16 k, d=64 as 2 MFMAs
    f32x4 sc4[4];
    #pragma unroll
    for (int tt = 0; tt < 4; tt++) {
      const int krow = (tt * 16 + r) * 64;
      bf16x8 kf0 = *reinterpret_cast<const bf16x8*>(kb + krow + ((g ^ rx) << 3));
      bf16x8 kf1 = *reinterpret_cast<const bf16x8*>(kb + krow + (((g + 4) ^ rx) << 3));
      f32x4 a = {};
      a = mfma16(kf0, qf0, a);
      a = mfma16(kf1, qf1, a);
      sc4[tt] = a;  // S[q=qbase+w*16+r][k=kt*64+tt*16+g*4+j]
    }

    // mask + exp (no max-sub) + row-sum + pack P -> pbuf
    const uint2 mu = *reinterpret_cast<const uint2*>(mrow + kt * 2);
    #pragma unroll
    for (int tt = 0; tt < 4; tt++) {
      const uint32_t mword = (tt < 2) ? mu.x : mu.y;
      const int bsh = (tt & 1) * 16 + g * 4;
      f32x4 e;
      #pragma unroll
      for (int j = 0; j < 4; j++) {
        float v = __builtin_exp2f(sc4[tt][j] * SCL);
        if ((mword >> (bsh + j)) & 1u) v = 0.f;
        e[j] = v;
        rs += v;
      }
      uint32_t lo = (uint32_t)(uint16_t)f2bf(e[0]) | ((uint32_t)(uint16_t)f2bf(e[1]) << 16);
      uint32_t hi = (uint32_t)(uint16_t)f2bf(e[2]) | ((uint32_t)(uint16_t)f2bf(e[3]) << 16);
      uint64_t pk = (uint64_t)lo | ((uint64_t)hi << 32);
      *reinterpret_cast<uint64_t*>(
          &pbuf[w][r * 64 + (((tt * 2 + (g >> 1)) ^ rx) << 3) + ((g & 1) << 2)]) = pk;
    }

    // PV: same-wave pbuf read (lgkm-ordered), V from LDS
    #pragma unroll
    for (int kt2 = 0; kt2 < 2; kt2++) {
      const int sl = ((kt2 * 4 + g) ^ rx) << 3;
      const bf16x8 paf = *reinterpret_cast<const bf16x8*>(&pbuf[w][r * 64 + sl]);
      #pragma unroll
      for (int n = 0; n < 4; n++) {
        const bf16x8 vf = *reinterpret_cast<const bf16x8*>(vb + (n * 16 + r) * 64 + sl);
        pacc[n] = mfma16(paf, vf, pacc[n]);
      }
    }

    __syncthreads();  // staged kt+1 resident; all waves done with buf[cur]
    cur ^= 1;
  }

  // row sums: combine the 4 g-groups
  rs += __shfl_xor(rs, 16);
  rs += __shfl_xor(rs, 32);

  float riv[4];
  #pragma unroll
  for (int j = 0; j < 4; j++) riv[j] = 1.0f / __shfl(rs, g * 4 + j);

  // ctx write: pacc[n][j] = ctx[q=qbase+w*16+g*4+j][d=n*16+r] (unnormalized)
  short* cbase = ctx + ((size_t)b * Sc + qbase + w * 16) * DMc + h * DHc;
  #pragma unroll
  for (int n = 0; n < 4; n++)
    #pragma unroll
    for (int j = 0; j < 4; j++)
      cbase[(size_t)(g * 4 + j) * DMc + n * 16 + r] = f2bf(pacc[n][j] * riv[j]);

  if (lane < 16) rsum[(size_t)bh * Sc + qbase + w * 16 + r] = rs;
}

// ---------------- attn writer: recompute scores, normalize, stream out --------
// grid (S/16, BH), block 512 (8 waves), wave w covers k [w*256,+256).
// No LDS, no barriers; rinv precomputed by k_flash -> pure write stream.
__global__ __launch_bounds__(512) void k_attnw(const short* __restrict__ Qb,
                                               const short* __restrict__ Kb,
                                               const uint32_t* __restrict__ pbits,
                                               const float* __restrict__ rsum,
                                               float* __restrict__ attn) {
  const int qb = blockIdx.x * 16;
  const int bh = blockIdx.y;
  const int b = bh >> 4;
  const int lane = threadIdx.x & 63, w = threadIdx.x >> 6;
  const int r = lane & 15, g = lane >> 4;

  const short* qrow = Qb + ((size_t)bh * Sc + qb + r) * DHc;
  const bf16x8 qf0 = *reinterpret_cast<const bf16x8*>(qrow + g * 8);
  const bf16x8 qf1 = *reinterpret_cast<const bf16x8*>(qrow + g * 8 + 32);

  const float rinv = 1.0f / rsum[(size_t)bh * Sc + qb + r];

  const uint32_t* mrow = pbits + ((size_t)b * Sc + qb + r) * (Sc / 32) + w * 8;
  const uint4 m0 = *reinterpret_cast<const uint4*>(mrow);
  const uint4 m1 = *reinterpret_cast<const uint4*>(mrow + 4);
  const uint32_t mw[8] = {m0.x, m0.y, m0.z, m0.w, m1.x, m1.y, m1.z, m1.w};

  const short* kbase = Kb + ((size_t)bh * Sc + w * 256) * DHc;
  float* out = attn + ((size_t)bh * Sc + qb + r) * Sc + w * 256;

  constexpr float SCL = 0.18033688f;  // log2(e)/8
  #pragma unroll
  for (int t = 0; t < 16; t++) {
    const short* krow = kbase + (size_t)(t * 16 + r) * DHc;
    bf16x8 kf0 = *reinterpret_cast<const bf16x8*>(krow + g * 8);
    bf16x8 kf1 = *reinterpret_cast<const bf16x8*>(krow + g * 8 + 32);
    f32x4 a = {};
    a = mfma16(kf0, qf0, a);
    a = mfma16(kf1, qf1, a);
    const uint32_t mword = mw[t >> 1];
    const int bsh = (t & 1) * 16 + g * 4;
    f32x4 o;
    #pragma unroll
    for (int j = 0; j < 4; j++) {
      float v = __builtin_exp2f(a[j] * SCL) * rinv;
      if ((mword >> (bsh + j)) & 1u) v = 0.f;
      o[j] = v;
    }
    __builtin_nontemporal_store(o, reinterpret_cast<f32x4*>(out + t * 16 + g * 4));
  }
}

// ---------------- residual + LayerNorm ----------------
__global__ __launch_bounds__(256) void k_ln(const float* __restrict__ y,
                                            const float* __restrict__ resid,
                                            float* __restrict__ out) {
  const int m = blockIdx.x, t = threadIdx.x;
  const float4 a = reinterpret_cast<const float4*>(y + (size_t)m * DMc)[t];
  const float4 b = reinterpret_cast<const float4*>(resid + (size_t)m * DMc)[t];
  float x0 = a.x + b.x, x1 = a.y + b.y, x2 = a.z + b.z, x3 = a.w + b.w;

  float s = x0 + x1 + x2 + x3;
  #pragma unroll
  for (int m2 = 1; m2 < 64; m2 <<= 1) s += __shfl_xor(s, m2);
  __shared__ float red[4];
  __shared__ float red2[4];
  const int w = t >> 6, lane = t & 63;
  if (lane == 0) red[w] = s;
  __syncthreads();
  const float mean = (red[0] + red[1] + red[2] + red[3]) * (1.0f / DMc);

  x0 -= mean; x1 -= mean; x2 -= mean; x3 -= mean;
  float s2 = x0 * x0 + x1 * x1 + x2 * x2 + x3 * x3;
  #pragma unroll
  for (int m2 = 1; m2 < 64; m2 <<= 1) s2 += __shfl_xor(s2, m2);
  if (lane == 0) red2[w] = s2;
  __syncthreads();
  const float var = (red2[0] + red2[1] + red2[2] + red2[3]) * (1.0f / DMc);
  const float rstd = rsqrtf(var + 1e-5f);

  float4 o;
  o.x = x0 * rstd; o.y = x1 * rstd; o.z = x2 * rstd; o.w = x3 * rstd;
  reinterpret_cast<float4*>(out + (size_t)m * DMc)[t] = o;
}

extern "C" void kernel_launch(void* const* d_in, const int* in_sizes, int n_in,
                              void* d_out, int out_size, void* d_ws, size_t ws_size,
                              hipStream_t stream) {
  const float* inQ = (const float*)d_in[0];
  const float* inK = (const float*)d_in[1];
  const float* inV = (const float*)d_in[2];
  const int*   msk = (const int*)d_in[3];
  const float* WQ  = (const float*)d_in[4];
  const float* WK  = (const float*)d_in[5];
  const float* WV  = (const float*)d_in[6];
  const float* Wfc = (const float*)d_in[7];

  float* out_ln   = (float*)d_out;                       // [B,S,1024] f32
  float* out_attn = out_ln + (size_t)Bc * Sc * DMc;      // [B,H,S,S] f32

  const size_t NX = (size_t)Bc * Sc * DMc;  // 8,388,608
  const size_t NW = (size_t)DMc * DMc;      // 1,048,576
  short* ws = (short*)d_ws;
  short* XbQ = ws;                 // bf16 inputs
  short* XbK = XbQ + NX;
  short* XbV = XbK + NX;
  short* WQb = XbV + NX;           // bf16 weights
  short* WKb = WQb + NW;
  short* WVb = WKb + NW;
  short* Wfb = WVb + NW;
  short* Qb  = Wfb + NW;           // [BH][S][64]
  short* Kb  = Qb + NX;            // [BH][S][64]
  short* Vt  = Kb + NX;            // [BH][64][S]
  uint32_t* pbits = (uint32_t*)(Vt + NX);        // [B][S][64 words], 2 MB
  float* rsum = (float*)(pbits + (size_t)Bc * Sc * (Sc / 32));  // [BH][S], 512 KB
  short* ctx = XbV;                // aliases XbV (dead after V-proj)
  float* y   = (float*)XbQ;        // aliases XbQ+XbK (dead after Q/K-proj)

  // 1) f32 -> bf16 conversions + mask pack
  k_cvt<<<dim3((unsigned)(NX / 1024)), 256, 0, stream>>>(inQ, XbQ);
  k_cvt<<<dim3((unsigned)(NX / 1024)), 256, 0, stream>>>(inK, XbK);
  k_cvt<<<dim3((unsigned)(NX / 1024)), 256, 0, stream>>>(inV, XbV);
  k_cvt<<<dim3((unsigned)(NW / 1024)), 256, 0, stream>>>(WQ, WQb);
  k_cvt<<<dim3((unsigned)(NW / 1024)), 256, 0, stream>>>(WK, WKb);
  k_cvt<<<dim3((unsigned)(NW / 1024)), 256, 0, stream>>>(WV, WVb);
  k_cvt<<<dim3((unsigned)(NW / 1024)), 256, 0, stream>>>(Wfc, Wfb);
  k_pack<<<dim3((unsigned)(Bc * Sc * (Sc / 256))), 256, 0, stream>>>(msk, pbits);

  // 2) projections (128x128 tiles)
  dim3 gp(Bc * Sc / 128, DMc / 128);  // (64, 8)
  k_gemm<<<gp, 256, 0, stream>>>(XbQ, WQb, (void*)Qb, 0);
  k_gemm<<<gp, 256, 0, stream>>>(XbK, WKb, (void*)Kb, 0);
  k_gemm<<<gp, 256, 0, stream>>>(XbV, WVb, (void*)Vt, 1);

  // 3) flash ctx (+ row sums)
  k_flash<<<dim3(Sc / 128, BHc), 512, 0, stream>>>(Qb, Kb, Vt, pbits, ctx, rsum);

  // 4) attn output stream (recompute + normalize)
  k_attnw<<<dim3(Sc / 16, BHc), 512, 0, stream>>>(Qb, Kb, pbits, rsum, out_attn);

  // 5) output projection -> y (f32)
  k_gemm<<<gp, 256, 0, stream>>>(ctx, Wfb, (void*)y, 2);

  // 6) residual + LayerNorm -> ln (output 0)
  k_ln<<<dim3(Bc * Sc), 256, 0, stream>>>(y, inQ, out_ln);
}

// Round 7
// 597.170 us; speedup vs baseline: 1.3812x; 1.0952x over previous
//
#include <hip/hip_runtime.h>
#include <cstdint>
#include <cstddef>

// Problem constants
constexpr int Bc  = 4;
constexpr int Sc  = 2048;
constexpr int DMc = 1024;   // d_model
constexpr int Hc  = 16;     // heads
constexpr int DHc = 64;     // head dim
constexpr int BHc = Bc * Hc;

typedef float f32x4  __attribute__((ext_vector_type(4)));
typedef short bf16x8 __attribute__((ext_vector_type(8)));

// f32 -> bf16 (RNE)
static __device__ __forceinline__ short f2bf(float x) {
  uint32_t u = __builtin_bit_cast(uint32_t, x);
  u += 0x7fffu + ((u >> 16) & 1u);
  return (short)(u >> 16);
}

static __device__ __forceinline__ f32x4 mfma16(bf16x8 a, bf16x8 b, f32x4 c) {
  return __builtin_amdgcn_mfma_f32_16x16x32_bf16(a, b, c, 0, 0, 0);
}

// async global->LDS, 16B per lane. LDS dest is wave-uniform base + lane*16.
static __device__ __forceinline__ void gload16(const short* g, short* l) {
  __builtin_amdgcn_global_load_lds(
      (const __attribute__((address_space(1))) void*)g,
      (__attribute__((address_space(3))) void*)l, 16, 0, 0);
}

// ---------------- dtype conversion: f32 -> bf16, 3 inputs in one launch -------
__global__ __launch_bounds__(256) void k_cvt3(const float* __restrict__ a,
                                              const float* __restrict__ b,
                                              const float* __restrict__ c,
                                              short* __restrict__ oa,
                                              short* __restrict__ ob,
                                              short* __restrict__ oc) {
  const float* in = blockIdx.y == 0 ? a : (blockIdx.y == 1 ? b : c);
  short* out      = blockIdx.y == 0 ? oa : (blockIdx.y == 1 ? ob : oc);
  int i = blockIdx.x * 256 + threadIdx.x;
  float4 v = reinterpret_cast<const float4*>(in)[i];
  short4 o;
  o.x = f2bf(v.x); o.y = f2bf(v.y); o.z = f2bf(v.z); o.w = f2bf(v.w);
  reinterpret_cast<short4*>(out)[i] = o;
}

// ---------------- weight conversion: 4 weights in one launch ----------------
__global__ __launch_bounds__(256) void k_cvtw(const float* __restrict__ a,
                                              const float* __restrict__ b,
                                              const float* __restrict__ c,
                                              const float* __restrict__ d,
                                              short* __restrict__ oa,
                                              short* __restrict__ ob,
                                              short* __restrict__ oc,
                                              short* __restrict__ od) {
  const int y = blockIdx.y;
  const float* in = y == 0 ? a : (y == 1 ? b : (y == 2 ? c : d));
  short* out      = y == 0 ? oa : (y == 1 ? ob : (y == 2 ? oc : od));
  int i = blockIdx.x * 256 + threadIdx.x;
  float4 v = reinterpret_cast<const float4*>(in)[i];
  short4 o;
  o.x = f2bf(v.x); o.y = f2bf(v.y); o.z = f2bf(v.z); o.w = f2bf(v.w);
  reinterpret_cast<short4*>(out)[i] = o;
}

// ---------------- mask bit-pack: int32 -> 1 bit ----------------
__global__ __launch_bounds__(256) void k_pack(const int* __restrict__ m,
                                              uint32_t* __restrict__ bits) {
  size_t i = (size_t)blockIdx.x * 256 + threadIdx.x;
  uint64_t b = __ballot(m[i] != 0);
  int lane = threadIdx.x & 63;
  if (lane == 0)  bits[i >> 5] = (uint32_t)b;
  if (lane == 32) bits[i >> 5] = (uint32_t)(b >> 32);
}

// ---------------- GEMM core: 128x128 tile, BK=32, 4 waves ----------------
// mode 0: out bf16 [BH][S][64]; mode 1: out bf16 [BH][64][S]; mode 2: out f32.
template <int MODE>
static __device__ __forceinline__ void gemm_body(const short* __restrict__ A,
                                                 const short* __restrict__ Bt,
                                                 void* __restrict__ out,
                                                 int bm, int bn) {
  __shared__ __align__(16) short lA[128 * 32];
  __shared__ __align__(16) short lB[128 * 32];
  const int lane = threadIdx.x & 63, w = threadIdx.x >> 6;
  const int wr = w >> 1, wc = w & 1;
  const int r = lane & 15, g = lane >> 4;
  const int lrow = lane >> 2;                       // staging row within 16-row chunk
  const int lsl  = (lane & 3) ^ ((lane >> 3) & 3);  // pre-swizzled global k-slot
  const int rsw  = (r >> 1) & 3;                    // read-side swizzle

  f32x4 acc[4][4] = {};
  const short* Ab = A + (size_t)bm * DMc;
  const short* Bb = Bt + (size_t)bn * DMc;

  for (int k0 = 0; k0 < DMc; k0 += 32) {
    __syncthreads();
    #pragma unroll
    for (int c = 0; c < 2; c++) {
      const int rbase = c * 64 + w * 16;
      gload16(Ab + (size_t)(rbase + lrow) * DMc + k0 + lsl * 8, lA + rbase * 32);
      gload16(Bb + (size_t)(rbase + lrow) * DMc + k0 + lsl * 8, lB + rbase * 32);
    }
    __syncthreads();

    bf16x8 af[4], bfr[4];
    #pragma unroll
    for (int i = 0; i < 4; i++) {
      const int arow = wr * 64 + i * 16 + r;
      af[i]  = *reinterpret_cast<const bf16x8*>(lA + arow * 32 + (g ^ rsw) * 8);
      const int brow = wc * 64 + i * 16 + r;
      bfr[i] = *reinterpret_cast<const bf16x8*>(lB + brow * 32 + (g ^ rsw) * 8);
    }
    #pragma unroll
    for (int i = 0; i < 4; i++)
      #pragma unroll
      for (int n = 0; n < 4; n++) acc[i][n] = mfma16(af[i], bfr[n], acc[i][n]);
  }

  #pragma unroll
  for (int i = 0; i < 4; i++) {
    #pragma unroll
    for (int n = 0; n < 4; n++) {
      const int col = bn + wc * 64 + n * 16 + r;
      #pragma unroll
      for (int j = 0; j < 4; j++) {
        const int m = bm + wr * 64 + i * 16 + g * 4 + j;
        if (MODE == 2) {
          reinterpret_cast<float*>(out)[(size_t)m * DMc + col] = acc[i][n][j];
        } else {
          const int b = m >> 11, s = m & (Sc - 1);
          const int h = col >> 6, d = col & (DHc - 1);
          size_t idx = (MODE == 1)
              ? ((size_t)(b * Hc + h) * DHc + d) * Sc + s     // Vt [BH][64][S]
              : ((size_t)(b * Hc + h) * Sc + s) * DHc + d;    // Q/K [BH][S][64]
          reinterpret_cast<short*>(out)[idx] = f2bf(acc[i][n][j]);
        }
      }
    }
  }
}

// Q/K/V projections in one launch (grid.z = 0/1/2)
__global__ __launch_bounds__(256) void k_gemmQKV(const short* __restrict__ XQ,
                                                 const short* __restrict__ XK,
                                                 const short* __restrict__ XV,
                                                 const short* __restrict__ WQ,
                                                 const short* __restrict__ WK,
                                                 const short* __restrict__ WV,
                                                 short* __restrict__ Q,
                                                 short* __restrict__ K,
                                                 short* __restrict__ V) {
  const int z = blockIdx.z;
  const int bm = blockIdx.x * 128, bn = blockIdx.y * 128;
  if (z == 0)      gemm_body<0>(XQ, WQ, (void*)Q, bm, bn);
  else if (z == 1) gemm_body<0>(XK, WK, (void*)K, bm, bn);
  else             gemm_body<1>(XV, WV, (void*)V, bm, bn);
}

// output projection (f32 out)
__global__ __launch_bounds__(256) void k_gemmO(const short* __restrict__ A,
                                               const short* __restrict__ Bt,
                                               float* __restrict__ out) {
  gemm_body<2>(A, Bt, (void*)out, blockIdx.x * 128, blockIdx.y * 128);
}

// ---------------- fused flash ctx + attn writer ----------------
// grid (S/128, BH), block 512 (8 waves). Wave w owns q-rows [qbase+w*16, +16).
// Phase 1: sweep K/V in 64-tiles (LDS double-buffered via global_load_lds),
//   P (unnormalized bf16) in per-wave LDS, accumulate ctx, full row-sums.
// Phase 2 (barrier-free, per-wave): recompute QK^T from L2-hot K, mask,
//   exp2*rinv, nontemporal f32x4 stores of normalized attn.
__global__ __launch_bounds__(512, 4) void k_flash2(const short* __restrict__ Qb,
                                                   const short* __restrict__ Kb,
                                                   const short* __restrict__ Vt,
                                                   const uint32_t* __restrict__ pbits,
                                                   short* __restrict__ ctx,
                                                   float* __restrict__ attn) {
  __shared__ __align__(16) short kbuf[2][4096];  // [64 k-rows][64 d] x dbuf, 16 KB
  __shared__ __align__(16) short vbuf[2][4096];  // [64 d-rows][64 k] x dbuf, 16 KB
  __shared__ __align__(16) short pbuf[8][1024];  // per-wave [16 q][64 k] bf16, 16 KB

  const int qbase = blockIdx.x * 128;
  const int bh = blockIdx.y;
  const int b = bh >> 4, h = bh & 15;
  const int tid = threadIdx.x;
  const int lane = tid & 63, w = tid >> 6;
  const int r = lane & 15, g = lane >> 4;
  const int rx = r & 7;

  // staging thread->element map: row = tid>>3, slot = (tid&7) ^ (row&7)
  const int srow = tid >> 3;
  const int sslot = (tid & 7) ^ (srow & 7);
  const short* ksrc = Kb + ((size_t)bh * Sc + srow) * DHc + sslot * 8;
  const short* vsrc = Vt + ((size_t)bh * DHc + srow) * Sc + sslot * 8;
  short* const kdst0 = &kbuf[0][w * 512];
  short* const kdst1 = &kbuf[1][w * 512];
  short* const vdst0 = &vbuf[0][w * 512];
  short* const vdst1 = &vbuf[1][w * 512];

  // Q fragment for my 16 rows (q = qbase + w*16 + r)
  const short* qrow = Qb + ((size_t)bh * Sc + qbase + w * 16 + r) * DHc;
  const bf16x8 qf0 = *reinterpret_cast<const bf16x8*>(qrow + g * 8);
  const bf16x8 qf1 = *reinterpret_cast<const bf16x8*>(qrow + g * 8 + 32);

  const uint32_t* mrow = pbits + ((size_t)b * Sc + qbase + w * 16 + r) * (Sc / 32);

  constexpr float SCL = 0.18033688f;  // log2(e)/8
  f32x4 pacc[4] = {};
  float rs = 0.f;

  // ---- phase 1: flash sweep ----
  gload16(ksrc, kdst0);
  gload16(vsrc, vdst0);
  __syncthreads();  // compiler drains vmcnt before barrier

  int cur = 0;
  for (int kt = 0; kt < 32; kt++) {
    if (kt + 1 < 32) {
      gload16(ksrc + (size_t)(kt + 1) * 64 * DHc, cur ? kdst0 : kdst1);
      gload16(vsrc + (kt + 1) * 64,               cur ? vdst0 : vdst1);
    }
    const short* kb = kbuf[cur];
    const short* vb = vbuf[cur];

    // QK^T: 4 t-tiles of 16 k, d=64 as 2 MFMAs
    f32x4 sc4[4];
    #pragma unroll
    for (int tt = 0; tt < 4; tt++) {
      const int krow = (tt * 16 + r) * 64;
      bf16x8 kf0 = *reinterpret_cast<const bf16x8*>(kb + krow + ((g ^ rx) << 3));
      bf16x8 kf1 = *reinterpret_cast<const bf16x8*>(kb + krow + (((g + 4) ^ rx) << 3));
      f32x4 a = {};
      a = mfma16(kf0, qf0, a);
      a = mfma16(kf1, qf1, a);
      sc4[tt] = a;  // S[q=qbase+w*16+r][k=kt*64+tt*16+g*4+j]
    }

    // mask + exp (no max-sub) + row-sum + pack P -> pbuf
    const uint2 mu = *reinterpret_cast<const uint2*>(mrow + kt * 2);
    #pragma unroll
    for (int tt = 0; tt < 4; tt++) {
      const uint32_t mword = (tt < 2) ? mu.x : mu.y;
      const int bsh = (tt & 1) * 16 + g * 4;
      f32x4 e;
      #pragma unroll
      for (int j = 0; j < 4; j++) {
        float v = __builtin_exp2f(sc4[tt][j] * SCL);
        if ((mword >> (bsh + j)) & 1u) v = 0.f;
        e[j] = v;
        rs += v;
      }
      uint32_t lo = (uint32_t)(uint16_t)f2bf(e[0]) | ((uint32_t)(uint16_t)f2bf(e[1]) << 16);
      uint32_t hi = (uint32_t)(uint16_t)f2bf(e[2]) | ((uint32_t)(uint16_t)f2bf(e[3]) << 16);
      uint64_t pk = (uint64_t)lo | ((uint64_t)hi << 32);
      *reinterpret_cast<uint64_t*>(
          &pbuf[w][r * 64 + (((tt * 2 + (g >> 1)) ^ rx) << 3) + ((g & 1) << 2)]) = pk;
    }

    // PV: same-wave pbuf read (lgkm-ordered), V from LDS
    #pragma unroll
    for (int kt2 = 0; kt2 < 2; kt2++) {
      const int sl = ((kt2 * 4 + g) ^ rx) << 3;
      const bf16x8 paf = *reinterpret_cast<const bf16x8*>(&pbuf[w][r * 64 + sl]);
      #pragma unroll
      for (int n = 0; n < 4; n++) {
        const bf16x8 vf = *reinterpret_cast<const bf16x8*>(vb + (n * 16 + r) * 64 + sl);
        pacc[n] = mfma16(paf, vf, pacc[n]);
      }
    }

    __syncthreads();  // staged kt+1 resident; all waves done with buf[cur]
    cur ^= 1;
  }

  // row sums: combine the 4 g-groups
  rs += __shfl_xor(rs, 16);
  rs += __shfl_xor(rs, 32);
  const float rinv = 1.0f / rs;   // rinv for row q = qbase + w*16 + r

  float riv[4];
  #pragma unroll
  for (int j = 0; j < 4; j++) riv[j] = 1.0f / __shfl(rs, g * 4 + j);

  // ctx write: pacc[n][j] = ctx[q=qbase+w*16+g*4+j][d=n*16+r]
  short* cbase = ctx + ((size_t)b * Sc + qbase + w * 16) * DMc + h * DHc;
  #pragma unroll
  for (int n = 0; n < 4; n++)
    #pragma unroll
    for (int j = 0; j < 4; j++)
      cbase[(size_t)(g * 4 + j) * DMc + n * 16 + r] = f2bf(pacc[n][j] * riv[j]);

  // ---- phase 2: normalized attn stream (per-wave, no barriers) ----
  const short* kbase = Kb + (size_t)bh * Sc * DHc;
  float* out = attn + ((size_t)bh * Sc + qbase + w * 16 + r) * Sc;
  #pragma unroll 2
  for (int kt = 0; kt < 32; kt++) {
    const uint2 mu = *reinterpret_cast<const uint2*>(mrow + kt * 2);
    #pragma unroll
    for (int tt = 0; tt < 4; tt++) {
      const short* krow = kbase + (size_t)(kt * 64 + tt * 16 + r) * DHc;
      bf16x8 kf0 = *reinterpret_cast<const bf16x8*>(krow + g * 8);
      bf16x8 kf1 = *reinterpret_cast<const bf16x8*>(krow + g * 8 + 32);
      f32x4 a = {};
      a = mfma16(kf0, qf0, a);
      a = mfma16(kf1, qf1, a);
      const uint32_t mword = (tt < 2) ? mu.x : mu.y;
      const int bsh = (tt & 1) * 16 + g * 4;
      f32x4 o;
      #pragma unroll
      for (int j = 0; j < 4; j++) {
        float v = __builtin_exp2f(a[j] * SCL) * rinv;
        if ((mword >> (bsh + j)) & 1u) v = 0.f;
        o[j] = v;
      }
      __builtin_nontemporal_store(
          o, reinterpret_cast<f32x4*>(out + kt * 64 + tt * 16 + g * 4));
    }
  }
}

// ---------------- residual + LayerNorm ----------------
__global__ __launch_bounds__(256) void k_ln(const float* __restrict__ y,
                                            const float* __restrict__ resid,
                                            float* __restrict__ out) {
  const int m = blockIdx.x, t = threadIdx.x;
  const float4 a = reinterpret_cast<const float4*>(y + (size_t)m * DMc)[t];
  const float4 b = reinterpret_cast<const float4*>(resid + (size_t)m * DMc)[t];
  float x0 = a.x + b.x, x1 = a.y + b.y, x2 = a.z + b.z, x3 = a.w + b.w;

  float s = x0 + x1 + x2 + x3;
  #pragma unroll
  for (int m2 = 1; m2 < 64; m2 <<= 1) s += __shfl_xor(s, m2);
  __shared__ float red[4];
  __shared__ float red2[4];
  const int w = t >> 6, lane = t & 63;
  if (lane == 0) red[w] = s;
  __syncthreads();
  const float mean = (red[0] + red[1] + red[2] + red[3]) * (1.0f / DMc);

  x0 -= mean; x1 -= mean; x2 -= mean; x3 -= mean;
  float s2 = x0 * x0 + x1 * x1 + x2 * x2 + x3 * x3;
  #pragma unroll
  for (int m2 = 1; m2 < 64; m2 <<= 1) s2 += __shfl_xor(s2, m2);
  if (lane == 0) red2[w] = s2;
  __syncthreads();
  const float var = (red2[0] + red2[1] + red2[2] + red2[3]) * (1.0f / DMc);
  const float rstd = rsqrtf(var + 1e-5f);

  float4 o;
  o.x = x0 * rstd; o.y = x1 * rstd; o.z = x2 * rstd; o.w = x3 * rstd;
  reinterpret_cast<float4*>(out + (size_t)m * DMc)[t] = o;
}

extern "C" void kernel_launch(void* const* d_in, const int* in_sizes, int n_in,
                              void* d_out, int out_size, void* d_ws, size_t ws_size,
                              hipStream_t stream) {
  const float* inQ = (const float*)d_in[0];
  const float* inK = (const float*)d_in[1];
  const float* inV = (const float*)d_in[2];
  const int*   msk = (const int*)d_in[3];
  const float* WQ  = (const float*)d_in[4];
  const float* WK  = (const float*)d_in[5];
  const float* WV  = (const float*)d_in[6];
  const float* Wfc = (const float*)d_in[7];

  float* out_ln   = (float*)d_out;                       // [B,S,1024] f32
  float* out_attn = out_ln + (size_t)Bc * Sc * DMc;      // [B,H,S,S] f32

  const size_t NX = (size_t)Bc * Sc * DMc;  // 8,388,608
  const size_t NW = (size_t)DMc * DMc;      // 1,048,576
  short* ws = (short*)d_ws;
  short* XbQ = ws;                 // bf16 inputs
  short* XbK = XbQ + NX;
  short* XbV = XbK + NX;
  short* WQb = XbV + NX;           // bf16 weights
  short* WKb = WQb + NW;
  short* WVb = WKb + NW;
  short* Wfb = WVb + NW;
  short* Qb  = Wfb + NW;           // [BH][S][64]
  short* Kb  = Qb + NX;            // [BH][S][64]
  short* Vt  = Kb + NX;            // [BH][64][S]
  uint32_t* pbits = (uint32_t*)(Vt + NX);  // [B][S][64 words], 2 MB
  short* ctx = XbV;                // aliases XbV (dead after V-proj)
  float* y   = (float*)XbQ;        // aliases XbQ+XbK (dead after Q/K-proj)

  // 1) conversions + mask pack (3 launches)
  k_cvt3<<<dim3((unsigned)(NX / 1024), 3), 256, 0, stream>>>(inQ, inK, inV, XbQ, XbK, XbV);
  k_cvtw<<<dim3((unsigned)(NW / 1024), 4), 256, 0, stream>>>(WQ, WK, WV, Wfc,
                                                             WQb, WKb, WVb, Wfb);
  k_pack<<<dim3((unsigned)(Bc * Sc * (Sc / 256))), 256, 0, stream>>>(msk, pbits);

  // 2) Q/K/V projections in one launch
  k_gemmQKV<<<dim3(Bc * Sc / 128, DMc / 128, 3), 256, 0, stream>>>(
      XbQ, XbK, XbV, WQb, WKb, WVb, Qb, Kb, Vt);

  // 3) fused flash ctx + attn stream
  k_flash2<<<dim3(Sc / 128, BHc), 512, 0, stream>>>(Qb, Kb, Vt, pbits, ctx, out_attn);

  // 4) output projection -> y (f32)
  k_gemmO<<<dim3(Bc * Sc / 128, DMc / 128), 256, 0, stream>>>(ctx, Wfb, y);

  // 5) residual + LayerNorm -> ln (output 0)
  k_ln<<<dim3(Bc * Sc), 256, 0, stream>>>(y, inQ, out_ln);
}

// Round 8
// 578.583 us; speedup vs baseline: 1.4256x; 1.0321x over previous
//
#include <hip/hip_runtime.h>
#include <cstdint>
#include <cstddef>

// Problem constants
constexpr int Bc  = 4;
constexpr int Sc  = 2048;
constexpr int DMc = 1024;   // d_model
constexpr int Hc  = 16;     // heads
constexpr int DHc = 64;     // head dim
constexpr int BHc = Bc * Hc;

typedef float f32x4  __attribute__((ext_vector_type(4)));
typedef short bf16x8 __attribute__((ext_vector_type(8)));

// f32 -> bf16 (RNE)
static __device__ __forceinline__ short f2bf(float x) {
  uint32_t u = __builtin_bit_cast(uint32_t, x);
  u += 0x7fffu + ((u >> 16) & 1u);
  return (short)(u >> 16);
}

static __device__ __forceinline__ f32x4 mfma16(bf16x8 a, bf16x8 b, f32x4 c) {
  return __builtin_amdgcn_mfma_f32_16x16x32_bf16(a, b, c, 0, 0, 0);
}

// async global->LDS, 16B per lane. LDS dest is wave-uniform base + lane*16.
static __device__ __forceinline__ void gload16(const short* g, short* l) {
  __builtin_amdgcn_global_load_lds(
      (const __attribute__((address_space(1))) void*)g,
      (__attribute__((address_space(3))) void*)l, 16, 0, 0);
}

// ---------------- dtype conversion: f32 -> bf16, 3 inputs in one launch -------
__global__ __launch_bounds__(256) void k_cvt3(const float* __restrict__ a,
                                              const float* __restrict__ b,
                                              const float* __restrict__ c,
                                              short* __restrict__ oa,
                                              short* __restrict__ ob,
                                              short* __restrict__ oc) {
  const float* in = blockIdx.y == 0 ? a : (blockIdx.y == 1 ? b : c);
  short* out      = blockIdx.y == 0 ? oa : (blockIdx.y == 1 ? ob : oc);
  int i = blockIdx.x * 256 + threadIdx.x;
  float4 v = reinterpret_cast<const float4*>(in)[i];
  short4 o;
  o.x = f2bf(v.x); o.y = f2bf(v.y); o.z = f2bf(v.z); o.w = f2bf(v.w);
  reinterpret_cast<short4*>(out)[i] = o;
}

// ---------------- weight conversion: 4 weights in one launch ----------------
__global__ __launch_bounds__(256) void k_cvtw(const float* __restrict__ a,
                                              const float* __restrict__ b,
                                              const float* __restrict__ c,
                                              const float* __restrict__ d,
                                              short* __restrict__ oa,
                                              short* __restrict__ ob,
                                              short* __restrict__ oc,
                                              short* __restrict__ od) {
  const int y = blockIdx.y;
  const float* in = y == 0 ? a : (y == 1 ? b : (y == 2 ? c : d));
  short* out      = y == 0 ? oa : (y == 1 ? ob : (y == 2 ? oc : od));
  int i = blockIdx.x * 256 + threadIdx.x;
  float4 v = reinterpret_cast<const float4*>(in)[i];
  short4 o;
  o.x = f2bf(v.x); o.y = f2bf(v.y); o.z = f2bf(v.z); o.w = f2bf(v.w);
  reinterpret_cast<short4*>(out)[i] = o;
}

// ---------------- mask bit-pack: int32 -> 1 bit ----------------
__global__ __launch_bounds__(256) void k_pack(const int* __restrict__ m,
                                              uint32_t* __restrict__ bits) {
  size_t i = (size_t)blockIdx.x * 256 + threadIdx.x;
  uint64_t b = __ballot(m[i] != 0);
  int lane = threadIdx.x & 63;
  if (lane == 0)  bits[i >> 5] = (uint32_t)b;
  if (lane == 32) bits[i >> 5] = (uint32_t)(b >> 32);
}

// ---------------- GEMM core: 128x128 tile, BK=64, 4 waves ----------------
// LDS [128 rows][64 cols] per matrix, 8-slot XOR swizzle (slot ^= row&7) applied
// on the pre-swizzled global source AND the ds_read address (both-sides rule).
// 32 MFMAs per barrier pair (BK=64) -> half the barrier drains of BK=32.
// mode 0: out bf16 [BH][S][64]; mode 1: out bf16 [BH][64][S]; mode 2: out f32.
template <int MODE>
static __device__ __forceinline__ void gemm_body(const short* __restrict__ A,
                                                 const short* __restrict__ Bt,
                                                 void* __restrict__ out,
                                                 int bm, int bn) {
  __shared__ __align__(16) short lA[128 * 64];
  __shared__ __align__(16) short lB[128 * 64];
  const int tid = threadIdx.x;
  const int lane = tid & 63, w = tid >> 6;
  const int wr = w >> 1, wc = w & 1;
  const int r = lane & 15, g = lane >> 4;

  // staging map: per round, wave w covers rows [rnd*32 + w*8, +8);
  // lane l -> row += l>>3, slot = (l&7) ^ (row&7) on the GLOBAL side.
  const int lrow8 = lane >> 3;           // 0..7
  const int lsl   = lane & 7;            // raw slot

  f32x4 acc[4][4] = {};
  const short* Ab = A + (size_t)bm * DMc;
  const short* Bb = Bt + (size_t)bn * DMc;

  for (int k0 = 0; k0 < DMc; k0 += 64) {
    __syncthreads();  // protect LDS from previous iteration's readers
    #pragma unroll
    for (int rnd = 0; rnd < 4; rnd++) {
      const int row = rnd * 32 + w * 8 + lrow8;
      const int slot = lsl ^ (row & 7);
      gload16(Ab + (size_t)row * DMc + k0 + slot * 8, lA + (rnd * 32 + w * 8) * 64);
      gload16(Bb + (size_t)row * DMc + k0 + slot * 8, lB + (rnd * 32 + w * 8) * 64);
    }
    __syncthreads();  // compiler drains vmcnt before barrier -> staged data ready

    #pragma unroll
    for (int kk = 0; kk < 2; kk++) {
      bf16x8 af[4], bfr[4];
      #pragma unroll
      for (int i = 0; i < 4; i++) {
        const int arow = wr * 64 + i * 16 + r;
        af[i] = *reinterpret_cast<const bf16x8*>(
            lA + arow * 64 + (((kk * 4 + g) ^ (arow & 7)) << 3));
        const int brow = wc * 64 + i * 16 + r;
        bfr[i] = *reinterpret_cast<const bf16x8*>(
            lB + brow * 64 + (((kk * 4 + g) ^ (brow & 7)) << 3));
      }
      #pragma unroll
      for (int i = 0; i < 4; i++)
        #pragma unroll
        for (int n = 0; n < 4; n++) acc[i][n] = mfma16(af[i], bfr[n], acc[i][n]);
    }
  }

  #pragma unroll
  for (int i = 0; i < 4; i++) {
    #pragma unroll
    for (int n = 0; n < 4; n++) {
      const int col = bn + wc * 64 + n * 16 + r;
      #pragma unroll
      for (int j = 0; j < 4; j++) {
        const int m = bm + wr * 64 + i * 16 + g * 4 + j;
        if (MODE == 2) {
          reinterpret_cast<float*>(out)[(size_t)m * DMc + col] = acc[i][n][j];
        } else {
          const int b = m >> 11, s = m & (Sc - 1);
          const int h = col >> 6, d = col & (DHc - 1);
          size_t idx = (MODE == 1)
              ? ((size_t)(b * Hc + h) * DHc + d) * Sc + s     // Vt [BH][64][S]
              : ((size_t)(b * Hc + h) * Sc + s) * DHc + d;    // Q/K [BH][S][64]
          reinterpret_cast<short*>(out)[idx] = f2bf(acc[i][n][j]);
        }
      }
    }
  }
}

// Q/K/V projections in one launch (grid.z = 0/1/2)
__global__ __launch_bounds__(256) void k_gemmQKV(const short* __restrict__ XQ,
                                                 const short* __restrict__ XK,
                                                 const short* __restrict__ XV,
                                                 const short* __restrict__ WQ,
                                                 const short* __restrict__ WK,
                                                 const short* __restrict__ WV,
                                                 short* __restrict__ Q,
                                                 short* __restrict__ K,
                                                 short* __restrict__ V) {
  const int z = blockIdx.z;
  const int bm = blockIdx.x * 128, bn = blockIdx.y * 128;
  if (z == 0)      gemm_body<0>(XQ, WQ, (void*)Q, bm, bn);
  else if (z == 1) gemm_body<0>(XK, WK, (void*)K, bm, bn);
  else             gemm_body<1>(XV, WV, (void*)V, bm, bn);
}

// output projection (f32 out)
__global__ __launch_bounds__(256) void k_gemmO(const short* __restrict__ A,
                                               const short* __restrict__ Bt,
                                               float* __restrict__ out) {
  gemm_body<2>(A, Bt, (void*)out, blockIdx.x * 128, blockIdx.y * 128);
}

// ---------------- fused flash ctx + attn writer ----------------
// grid (S/128, BH), block 512 (8 waves). Wave w owns q-rows [qbase+w*16, +16).
// Phase 1: sweep K/V in 64-tiles (LDS double-buffered via global_load_lds),
//   P (unnormalized bf16) in per-wave LDS, accumulate ctx, full row-sums.
// Phase 2 (barrier-free, per-wave): recompute QK^T from L2-hot K, mask,
//   exp2*rinv, nontemporal f32x4 stores of normalized attn.
__global__ __launch_bounds__(512, 4) void k_flash2(const short* __restrict__ Qb,
                                                   const short* __restrict__ Kb,
                                                   const short* __restrict__ Vt,
                                                   const uint32_t* __restrict__ pbits,
                                                   short* __restrict__ ctx,
                                                   float* __restrict__ attn) {
  __shared__ __align__(16) short kbuf[2][4096];  // [64 k-rows][64 d] x dbuf, 16 KB
  __shared__ __align__(16) short vbuf[2][4096];  // [64 d-rows][64 k] x dbuf, 16 KB
  __shared__ __align__(16) short pbuf[8][1024];  // per-wave [16 q][64 k] bf16, 16 KB

  const int qbase = blockIdx.x * 128;
  const int bh = blockIdx.y;
  const int b = bh >> 4, h = bh & 15;
  const int tid = threadIdx.x;
  const int lane = tid & 63, w = tid >> 6;
  const int r = lane & 15, g = lane >> 4;
  const int rx = r & 7;

  // staging thread->element map: row = tid>>3, slot = (tid&7) ^ (row&7)
  const int srow = tid >> 3;
  const int sslot = (tid & 7) ^ (srow & 7);
  const short* ksrc = Kb + ((size_t)bh * Sc + srow) * DHc + sslot * 8;
  const short* vsrc = Vt + ((size_t)bh * DHc + srow) * Sc + sslot * 8;
  short* const kdst0 = &kbuf[0][w * 512];
  short* const kdst1 = &kbuf[1][w * 512];
  short* const vdst0 = &vbuf[0][w * 512];
  short* const vdst1 = &vbuf[1][w * 512];

  // Q fragment for my 16 rows (q = qbase + w*16 + r)
  const short* qrow = Qb + ((size_t)bh * Sc + qbase + w * 16 + r) * DHc;
  const bf16x8 qf0 = *reinterpret_cast<const bf16x8*>(qrow + g * 8);
  const bf16x8 qf1 = *reinterpret_cast<const bf16x8*>(qrow + g * 8 + 32);

  const uint32_t* mrow = pbits + ((size_t)b * Sc + qbase + w * 16 + r) * (Sc / 32);

  constexpr float SCL = 0.18033688f;  // log2(e)/8
  f32x4 pacc[4] = {};
  float rs = 0.f;

  // ---- phase 1: flash sweep ----
  gload16(ksrc, kdst0);
  gload16(vsrc, vdst0);
  __syncthreads();  // compiler drains vmcnt before barrier

  int cur = 0;
  for (int kt = 0; kt < 32; kt++) {
    if (kt + 1 < 32) {
      gload16(ksrc + (size_t)(kt + 1) * 64 * DHc, cur ? kdst0 : kdst1);
      gload16(vsrc + (kt + 1) * 64,               cur ? vdst0 : vdst1);
    }
    const short* kb = kbuf[cur];
    const short* vb = vbuf[cur];

    // QK^T: 4 t-tiles of 16 k, d=64 as 2 MFMAs
    f32x4 sc4[4];
    #pragma unroll
    for (int tt = 0; tt < 4; tt++) {
      const int krow = (tt * 16 + r) * 64;
      bf16x8 kf0 = *reinterpret_cast<const bf16x8*>(kb + krow + ((g ^ rx) << 3));
      bf16x8 kf1 = *reinterpret_cast<const bf16x8*>(kb + krow + (((g + 4) ^ rx) << 3));
      f32x4 a = {};
      a = mfma16(kf0, qf0, a);
      a = mfma16(kf1, qf1, a);
      sc4[tt] = a;  // S[q=qbase+w*16+r][k=kt*64+tt*16+g*4+j]
    }

    // mask + exp (no max-sub) + row-sum + pack P -> pbuf
    const uint2 mu = *reinterpret_cast<const uint2*>(mrow + kt * 2);
    #pragma unroll
    for (int tt = 0; tt < 4; tt++) {
      const uint32_t mword = (tt < 2) ? mu.x : mu.y;
      const int bsh = (tt & 1) * 16 + g * 4;
      f32x4 e;
      #pragma unroll
      for (int j = 0; j < 4; j++) {
        float v = __builtin_exp2f(sc4[tt][j] * SCL);
        if ((mword >> (bsh + j)) & 1u) v = 0.f;
        e[j] = v;
        rs += v;
      }
      uint32_t lo = (uint32_t)(uint16_t)f2bf(e[0]) | ((uint32_t)(uint16_t)f2bf(e[1]) << 16);
      uint32_t hi = (uint32_t)(uint16_t)f2bf(e[2]) | ((uint32_t)(uint16_t)f2bf(e[3]) << 16);
      uint64_t pk = (uint64_t)lo | ((uint64_t)hi << 32);
      *reinterpret_cast<uint64_t*>(
          &pbuf[w][r * 64 + (((tt * 2 + (g >> 1)) ^ rx) << 3) + ((g & 1) << 2)]) = pk;
    }

    // PV: same-wave pbuf read (lgkm-ordered), V from LDS
    #pragma unroll
    for (int kt2 = 0; kt2 < 2; kt2++) {
      const int sl = ((kt2 * 4 + g) ^ rx) << 3;
      const bf16x8 paf = *reinterpret_cast<const bf16x8*>(&pbuf[w][r * 64 + sl]);
      #pragma unroll
      for (int n = 0; n < 4; n++) {
        const bf16x8 vf = *reinterpret_cast<const bf16x8*>(vb + (n * 16 + r) * 64 + sl);
        pacc[n] = mfma16(paf, vf, pacc[n]);
      }
    }

    __syncthreads();  // staged kt+1 resident; all waves done with buf[cur]
    cur ^= 1;
  }

  // row sums: combine the 4 g-groups
  rs += __shfl_xor(rs, 16);
  rs += __shfl_xor(rs, 32);
  const float rinv = 1.0f / rs;   // rinv for row q = qbase + w*16 + r

  float riv[4];
  #pragma unroll
  for (int j = 0; j < 4; j++) riv[j] = 1.0f / __shfl(rs, g * 4 + j);

  // ctx write: pacc[n][j] = ctx[q=qbase+w*16+g*4+j][d=n*16+r]
  short* cbase = ctx + ((size_t)b * Sc + qbase + w * 16) * DMc + h * DHc;
  #pragma unroll
  for (int n = 0; n < 4; n++)
    #pragma unroll
    for (int j = 0; j < 4; j++)
      cbase[(size_t)(g * 4 + j) * DMc + n * 16 + r] = f2bf(pacc[n][j] * riv[j]);

  // ---- phase 2: normalized attn stream (per-wave, no barriers) ----
  const short* kbase = Kb + (size_t)bh * Sc * DHc;
  float* out = attn + ((size_t)bh * Sc + qbase + w * 16 + r) * Sc;
  #pragma unroll 2
  for (int kt = 0; kt < 32; kt++) {
    const uint2 mu = *reinterpret_cast<const uint2*>(mrow + kt * 2);
    #pragma unroll
    for (int tt = 0; tt < 4; tt++) {
      const short* krow = kbase + (size_t)(kt * 64 + tt * 16 + r) * DHc;
      bf16x8 kf0 = *reinterpret_cast<const bf16x8*>(krow + g * 8);
      bf16x8 kf1 = *reinterpret_cast<const bf16x8*>(krow + g * 8 + 32);
      f32x4 a = {};
      a = mfma16(kf0, qf0, a);
      a = mfma16(kf1, qf1, a);
      const uint32_t mword = (tt < 2) ? mu.x : mu.y;
      const int bsh = (tt & 1) * 16 + g * 4;
      f32x4 o;
      #pragma unroll
      for (int j = 0; j < 4; j++) {
        float v = __builtin_exp2f(a[j] * SCL) * rinv;
        if ((mword >> (bsh + j)) & 1u) v = 0.f;
        o[j] = v;
      }
      __builtin_nontemporal_store(
          o, reinterpret_cast<f32x4*>(out + kt * 64 + tt * 16 + g * 4));
    }
  }
}

// ---------------- residual + LayerNorm ----------------
__global__ __launch_bounds__(256) void k_ln(const float* __restrict__ y,
                                            const float* __restrict__ resid,
                                            float* __restrict__ out) {
  const int m = blockIdx.x, t = threadIdx.x;
  const float4 a = reinterpret_cast<const float4*>(y + (size_t)m * DMc)[t];
  const float4 b = reinterpret_cast<const float4*>(resid + (size_t)m * DMc)[t];
  float x0 = a.x + b.x, x1 = a.y + b.y, x2 = a.z + b.z, x3 = a.w + b.w;

  float s = x0 + x1 + x2 + x3;
  #pragma unroll
  for (int m2 = 1; m2 < 64; m2 <<= 1) s += __shfl_xor(s, m2);
  __shared__ float red[4];
  __shared__ float red2[4];
  const int w = t >> 6, lane = t & 63;
  if (lane == 0) red[w] = s;
  __syncthreads();
  const float mean = (red[0] + red[1] + red[2] + red[3]) * (1.0f / DMc);

  x0 -= mean; x1 -= mean; x2 -= mean; x3 -= mean;
  float s2 = x0 * x0 + x1 * x1 + x2 * x2 + x3 * x3;
  #pragma unroll
  for (int m2 = 1; m2 < 64; m2 <<= 1) s2 += __shfl_xor(s2, m2);
  if (lane == 0) red2[w] = s2;
  __syncthreads();
  const float var = (red2[0] + red2[1] + red2[2] + red2[3]) * (1.0f / DMc);
  const float rstd = rsqrtf(var + 1e-5f);

  float4 o;
  o.x = x0 * rstd; o.y = x1 * rstd; o.z = x2 * rstd; o.w = x3 * rstd;
  reinterpret_cast<float4*>(out + (size_t)m * DMc)[t] = o;
}

extern "C" void kernel_launch(void* const* d_in, const int* in_sizes, int n_in,
                              void* d_out, int out_size, void* d_ws, size_t ws_size,
                              hipStream_t stream) {
  const float* inQ = (const float*)d_in[0];
  const float* inK = (const float*)d_in[1];
  const float* inV = (const float*)d_in[2];
  const int*   msk = (const int*)d_in[3];
  const float* WQ  = (const float*)d_in[4];
  const float* WK  = (const float*)d_in[5];
  const float* WV  = (const float*)d_in[6];
  const float* Wfc = (const float*)d_in[7];

  float* out_ln   = (float*)d_out;                       // [B,S,1024] f32
  float* out_attn = out_ln + (size_t)Bc * Sc * DMc;      // [B,H,S,S] f32

  const size_t NX = (size_t)Bc * Sc * DMc;  // 8,388,608
  const size_t NW = (size_t)DMc * DMc;      // 1,048,576
  short* ws = (short*)d_ws;
  short* XbQ = ws;                 // bf16 inputs
  short* XbK = XbQ + NX;
  short* XbV = XbK + NX;
  short* WQb = XbV + NX;           // bf16 weights
  short* WKb = WQb + NW;
  short* WVb = WKb + NW;
  short* Wfb = WVb + NW;
  short* Qb  = Wfb + NW;           // [BH][S][64]
  short* Kb  = Qb + NX;            // [BH][S][64]
  short* Vt  = Kb + NX;            // [BH][64][S]
  uint32_t* pbits = (uint32_t*)(Vt + NX);  // [B][S][64 words], 2 MB
  short* ctx = XbV;                // aliases XbV (dead after V-proj)
  float* y   = (float*)XbQ;        // aliases XbQ+XbK (dead after Q/K-proj)

  // 1) conversions + mask pack (3 launches)
  k_cvt3<<<dim3((unsigned)(NX / 1024), 3), 256, 0, stream>>>(inQ, inK, inV, XbQ, XbK, XbV);
  k_cvtw<<<dim3((unsigned)(NW / 1024), 4), 256, 0, stream>>>(WQ, WK, WV, Wfc,
                                                             WQb, WKb, WVb, Wfb);
  k_pack<<<dim3((unsigned)(Bc * Sc * (Sc / 256))), 256, 0, stream>>>(msk, pbits);

  // 2) Q/K/V projections in one launch
  k_gemmQKV<<<dim3(Bc * Sc / 128, DMc / 128, 3), 256, 0, stream>>>(
      XbQ, XbK, XbV, WQb, WKb, WVb, Qb, Kb, Vt);

  // 3) fused flash ctx + attn stream
  k_flash2<<<dim3(Sc / 128, BHc), 512, 0, stream>>>(Qb, Kb, Vt, pbits, ctx, out_attn);

  // 4) output projection -> y (f32)
  k_gemmO<<<dim3(Bc * Sc / 128, DMc / 128), 256, 0, stream>>>(ctx, Wfb, y);

  // 5) residual + LayerNorm -> ln (output 0)
  k_ln<<<dim3(Bc * Sc), 256, 0, stream>>>(y, inQ, out_ln);
}